// Round 6
// baseline (3764.894 us; speedup 1.0000x reference)
//
#include <hip/hip_runtime.h>
#include <cstdint>

// ---------------------------------------------------------------------------
// SimpleViT forward on gfx950. bf16 MFMA GEMMs, f32 residual stream.
// R6: single-barrier double-buffered K-loop (BK=32, 2x(8K+8K) LDS): order is
//     [barrier -> issue g2lds(next) -> ds_read(cur) -> MFMA], so the
//     vmcnt(0)-at-barrier drains loads issued a full iteration earlier.
//     XOR swizzle phys=quad^((row>>1)&3) keeps ds_read_b128 conflict-free.
//     V-transpose fused into QKV epilogue (EPI 6). Split-K partials, XCD
//     swizzle, fast GELU kept.
// ---------------------------------------------------------------------------

typedef __bf16 bf16_t;
typedef __bf16 bf16x8 __attribute__((ext_vector_type(8)));
typedef __bf16 bf16x4 __attribute__((ext_vector_type(4)));
typedef float  f32x4  __attribute__((ext_vector_type(4)));

#define NLAYER 12
#define BMPAD 56           // M-tiles padded to mult of 8 -> XCD co-location
#define PSTRIDE 4816896l   // elements per partial buffer [6272][768]

__device__ __forceinline__ void g2lds16(const void* g, void* l) {
  __builtin_amdgcn_global_load_lds(
      (const __attribute__((address_space(1))) void*)g,
      (__attribute__((address_space(3))) void*)l, 16, 0, 0);
}

// ---------------------------------------------------------------------------
// Weight transpose + f32->bf16: in [R][C] f32 -> out [C][R] bf16 (batched).
// ---------------------------------------------------------------------------
__global__ __launch_bounds__(256) void tcvt(
    const float* __restrict__ in, bf16_t* __restrict__ out,
    int R, int C, long inStride, long outOuter, long outInner, int innerN)
{
  int bi = blockIdx.z;
  in  += (long)bi * inStride;
  out += (long)(bi / innerN) * outOuter + (long)(bi % innerN) * outInner;
  __shared__ float t[32][33];
  int c0 = blockIdx.x * 32, r0 = blockIdx.y * 32;
  int tx = threadIdx.x, ty = threadIdx.y;
  #pragma unroll
  for (int i = ty; i < 32; i += 8) {
    int r = r0 + i, c = c0 + tx;
    if (r < R && c < C) t[i][tx] = in[(long)r * C + c];
  }
  __syncthreads();
  #pragma unroll
  for (int i = ty; i < 32; i += 8) {
    int c = c0 + i, r = r0 + tx;
    if (r < R && c < C) out[(long)c * R + r] = (bf16_t)t[tx][i];
  }
}

// ---------------------------------------------------------------------------
// Patchify: x[32,3,224,224] f32 -> patches[6272,768] bf16
// ---------------------------------------------------------------------------
__global__ __launch_bounds__(256) void patchify(
    const float* __restrict__ x, bf16_t* __restrict__ patches)
{
  int idx = blockIdx.x * 256 + threadIdx.x;
  int bt = idx / 768, pd = idx % 768;
  int b = bt / 196, t = bt % 196;
  int gh = t / 14, gw = t % 14;
  int p1 = pd / 48, rem = pd % 48;
  int p2 = rem / 3, c = rem % 3;
  float v = x[(((long)(b * 3 + c) * 224) + gh * 16 + p1) * 224 + gw * 16 + p2];
  patches[idx] = (bf16_t)v;
}

// ---------------------------------------------------------------------------
// h init: h[b][t][d] = posemb(t,d) + embed_b[d]
// ---------------------------------------------------------------------------
__global__ __launch_bounds__(256) void hinit(
    const float* __restrict__ eb, float* __restrict__ h)
{
  int idx = blockIdx.x * 256 + threadIdx.x;      // 0 .. 196*768-1
  int t = idx / 768, d = idx % 768;
  int gh = t / 14, gw = t % 14;
  int quadrant = d / 192, i = d % 192;
  float omega = powf(10000.0f, -(float)i / 191.0f);
  float arg = (quadrant < 2 ? (float)gw : (float)gh) * omega;
  float pv = ((quadrant & 1) == 0) ? sinf(arg) : cosf(arg);
  float v = pv + eb[d];
  #pragma unroll
  for (int b = 0; b < 32; ++b) h[(long)b * 150528 + idx] = v;
}

// ---------------------------------------------------------------------------
// Zero Vt pad region s in [196,224) for all (bh,e): 384*64*28 elems.
// ---------------------------------------------------------------------------
__global__ __launch_bounds__(256) void vpad(bf16_t* __restrict__ Vt)
{
  int i = blockIdx.x * 256 + threadIdx.x;        // 0 .. 688127
  int s = 196 + (i % 28), rest = i / 28;         // rest = bh*64+e
  Vt[(long)rest * 224 + s] = (bf16_t)0.0f;
}

// ---------------------------------------------------------------------------
// Fused residual + LayerNorm: h += sum(partials) + bias; xn = LN(h)*g+b.
// ---------------------------------------------------------------------------
__global__ __launch_bounds__(256) void ln_fuse(
    float* __restrict__ h, const bf16_t* __restrict__ pbuf, int nparts,
    const float* __restrict__ bias, const float* __restrict__ g,
    const float* __restrict__ bb, bf16_t* __restrict__ xn)
{
  int row = blockIdx.x * 4 + (threadIdx.x >> 6);
  int lane = threadIdx.x & 63;
  float* hr = h + (long)row * 768;
  const bf16_t* pr = pbuf + (long)row * 768;
  float4 v[3];
  float s = 0.f, s2 = 0.f;
  #pragma unroll
  for (int i = 0; i < 3; ++i) {
    int c4 = lane + 64 * i;
    float4 hv = ((const float4*)hr)[c4];
    float4 acc = {0.f, 0.f, 0.f, 0.f};
    for (int pp = 0; pp < nparts; ++pp) {
      bf16x4 q = *(const bf16x4*)(pr + (long)pp * PSTRIDE + c4 * 4);
      acc.x += (float)q[0]; acc.y += (float)q[1];
      acc.z += (float)q[2]; acc.w += (float)q[3];
    }
    if (bias) {
      float4 bv = ((const float4*)bias)[c4];
      acc.x += bv.x; acc.y += bv.y; acc.z += bv.z; acc.w += bv.w;
    }
    hv.x += acc.x; hv.y += acc.y; hv.z += acc.z; hv.w += acc.w;
    ((float4*)hr)[c4] = hv;
    v[i] = hv;
    s  += hv.x + hv.y + hv.z + hv.w;
    s2 += hv.x * hv.x + hv.y * hv.y + hv.z * hv.z + hv.w * hv.w;
  }
  #pragma unroll
  for (int d = 1; d < 64; d <<= 1) {
    s  += __shfl_xor(s, d, 64);
    s2 += __shfl_xor(s2, d, 64);
  }
  float mu = s * (1.0f / 768.0f);
  float var = s2 * (1.0f / 768.0f) - mu * mu;
  float rs = rsqrtf(var + 1e-5f);
  uint2* outv = (uint2*)(xn + (long)row * 768);
  const float4* gv = (const float4*)g;
  const float4* bv2 = (const float4*)bb;
  #pragma unroll
  for (int i = 0; i < 3; ++i) {
    int c4 = lane + 64 * i;
    float4 gg = gv[c4], b4 = bv2[c4];
    union { bf16_t q[4]; uint2 u; } pk;
    pk.q[0] = (bf16_t)((v[i].x - mu) * rs * gg.x + b4.x);
    pk.q[1] = (bf16_t)((v[i].y - mu) * rs * gg.y + b4.y);
    pk.q[2] = (bf16_t)((v[i].z - mu) * rs * gg.z + b4.z);
    pk.q[3] = (bf16_t)((v[i].w - mu) * rs * gg.w + b4.w);
    outv[c4] = pk.u;
  }
}

// ---------------------------------------------------------------------------
// tanh-form GELU
// ---------------------------------------------------------------------------
__device__ __forceinline__ float gelu_fast(float x) {
  float y = 0.7978845608f * (x + 0.044715f * x * x * x);
  float e = __expf(2.0f * y);
  float t = 1.0f - 2.0f / (e + 1.0f);
  return 0.5f * x * (1.0f + t);
}

// ---------------------------------------------------------------------------
// Main GEMM: C[M,N] = A[M,K] * Bt[N,K]^T.  128x128 tile, 4 waves.
// Double-buffered BK=32, ONE barrier per iteration:
//   [barrier -> g2lds(next buf) -> ds_read(cur) -> MFMA]
// LDS row = 32 elems (64B) = 4 granules; phys granule g of row r holds
// logical g^((r>>1)&3)  (8 start-bank groups x 2 lanes -> conflict-free).
// 1-D grid, lin = (bn*KS + ks)*BMPAD + bm  -> same bm => same XCD (lin%8).
// EPI: 0 = bf16 store; 3 = gelu->bf16 (MLP1); 4 = f32 masked (head);
//      5 = bf16 partial at bout+ks*PSTRIDE; 6 = QKV: q/k -> bout, V -> vout^T
// ---------------------------------------------------------------------------
template <int EPI, int KTOT, int KS>
__global__ __launch_bounds__(256, 4) void gemm_bt(
    const bf16_t* __restrict__ A, const bf16_t* __restrict__ Bt,
    int ldc, int Mstore, int Nstore,
    const float* __restrict__ bias,
    float* __restrict__ fout, bf16_t* __restrict__ bout,
    bf16_t* __restrict__ vout)
{
  int lin = blockIdx.x;
  int bm = lin % BMPAD;
  if (bm * 128 >= Mstore) return;
  int rest = lin / BMPAD;
  int ks = rest % KS;
  int bn = rest / KS;
  constexpr int Ksl = KTOT / KS;
  constexpr int NIT = Ksl / 32;
  int k0 = ks * Ksl;

  __shared__ __align__(16) bf16_t As[2][128 * 32];
  __shared__ __align__(16) bf16_t Bs[2][128 * 32];
  int tid = threadIdx.x;
  int wave = tid >> 6, lane = tid & 63, quad = lane >> 4, l16 = lane & 15;
  int wm = wave >> 1, wn = wave & 1;
  const bf16_t* Ab = A + (long)bm * 128 * KTOT + k0;
  const bf16_t* Bb = Bt + (long)bn * 128 * KTOT + k0;

  f32x4 zero = {0.f, 0.f, 0.f, 0.f};
  f32x4 acc[4][4];
  #pragma unroll
  for (int i = 0; i < 4; ++i)
    #pragma unroll
    for (int j = 0; j < 4; ++j) acc[i][j] = zero;

  // staging map: 2 calls per matrix; call c covers row c*64 + tid/4,
  // thread writes phys granule tid&3; source logical = (tid&3)^((row>>1)&3)
  int srow = tid >> 2;                         // 0..63
  int sgcol = ((tid & 3) ^ ((srow >> 1) & 3)) * 8;
  int ldst = tid * 16;                         // byte offset within 4KB call
  long ag0 = (long)srow * KTOT + sgcol;
  long ag1 = (long)(64 + srow) * KTOT + sgcol;

  // fragment LDS offsets (elems): phys = quad ^ ((l16>>1)&3) (row-invariant)
  int physf = (quad ^ ((l16 >> 1) & 3)) * 8;
  int aoff[4], boff[4];
  #pragma unroll
  for (int i = 0; i < 4; ++i) {
    aoff[i] = (wm * 64 + i * 16 + l16) * 32 + physf;
    boff[i] = (wn * 64 + i * 16 + l16) * 32 + physf;
  }

  // prologue: stage tile 0 into buf 0
  g2lds16(Ab + ag0, (char*)As[0] + ldst);
  g2lds16(Ab + ag1, (char*)As[0] + 4096 + ldst);
  g2lds16(Bb + ag0, (char*)Bs[0] + ldst);
  g2lds16(Bb + ag1, (char*)Bs[0] + 4096 + ldst);

  for (int it = 0; it < NIT; ++it) {
    int cur = it & 1;
    __syncthreads();   // drains vmcnt(0): cur's loads issued one iter ago
    if (it + 1 < NIT) {
      int kt = (it + 1) * 32;
      g2lds16(Ab + ag0 + kt, (char*)As[cur ^ 1] + ldst);
      g2lds16(Ab + ag1 + kt, (char*)As[cur ^ 1] + 4096 + ldst);
      g2lds16(Bb + ag0 + kt, (char*)Bs[cur ^ 1] + ldst);
      g2lds16(Bb + ag1 + kt, (char*)Bs[cur ^ 1] + 4096 + ldst);
    }
    bf16x8 af[4], bfr[4];
    #pragma unroll
    for (int i = 0; i < 4; ++i) af[i] = *(const bf16x8*)(As[cur] + aoff[i]);
    #pragma unroll
    for (int j = 0; j < 4; ++j) bfr[j] = *(const bf16x8*)(Bs[cur] + boff[j]);
    #pragma unroll
    for (int i = 0; i < 4; ++i)
      #pragma unroll
      for (int j = 0; j < 4; ++j)
        acc[i][j] = __builtin_amdgcn_mfma_f32_16x16x32_bf16(af[i], bfr[j], acc[i][j], 0, 0, 0);
  }

  int m0 = bm * 128 + wm * 64, n0 = bn * 128 + wn * 64;
  #pragma unroll
  for (int i = 0; i < 4; ++i)
    #pragma unroll
    for (int j = 0; j < 4; ++j)
      #pragma unroll
      for (int r = 0; r < 4; ++r) {
        int row = m0 + i * 16 + quad * 4 + r;
        int col = n0 + j * 16 + l16;
        if (row >= Mstore || col >= Nstore) continue;
        float v = acc[i][j][r];
        if (EPI == 0) {
          bout[(long)row * ldc + col] = (bf16_t)v;
        } else if (EPI == 3) {
          bout[(long)row * ldc + col] = (bf16_t)gelu_fast(v + bias[col]);
        } else if (EPI == 4) {
          fout[(long)row * ldc + col] = v;
        } else if (EPI == 5) {
          bout[(long)ks * PSTRIDE + (long)row * ldc + col] = (bf16_t)v;
        } else {  // EPI 6: QKV fused with V-transpose
          if (col < 1536) {
            bout[(long)row * ldc + col] = (bf16_t)v;
          } else {
            int hh = (col - 1536) >> 6, e = (col - 1536) & 63;
            int bb2 = row / 196, s = row - bb2 * 196;
            vout[((long)(bb2 * 12 + hh) * 64 + e) * 224 + s] = (bf16_t)v;
          }
        }
      }
}

// ---------------------------------------------------------------------------
// Fused attention: scores -> softmax -> P in LDS -> P@V -> att.
// ---------------------------------------------------------------------------
__global__ __launch_bounds__(64) void attn_fused(
    const bf16_t* __restrict__ qkv, const bf16_t* __restrict__ Vt,
    bf16_t* __restrict__ att)
{
  __shared__ __align__(16) bf16_t Pl[16 * 232];
  int mt = blockIdx.x, bh = blockIdx.y;
  int b = bh / 12, h = bh % 12;
  int lane = threadIdx.x, quad = lane >> 4, l16 = lane & 15;

  #pragma unroll
  for (int i = 0; i < 4; ++i) {
    int idx = lane + 64 * i;
    Pl[(idx >> 4) * 232 + 208 + (idx & 15)] = (bf16_t)0.0f;
  }

  f32x4 zero = {0.f, 0.f, 0.f, 0.f};
  f32x4 acc[13];
  #pragma unroll
  for (int nt = 0; nt < 13; ++nt) acc[nt] = zero;

  long qoff = (long)(b * 196 + mt * 16 + l16) * 2304 + h * 64;
  #pragma unroll
  for (int kk = 0; kk < 2; ++kk) {
    bf16x8 a = *(const bf16x8*)(qkv + qoff + kk * 32 + quad * 8);
    #pragma unroll
    for (int nt = 0; nt < 13; ++nt) {
      long koff = (long)(b * 196 + nt * 16 + l16) * 2304 + 768 + h * 64 + kk * 32 + quad * 8;
      bf16x8 bb = *(const bf16x8*)(qkv + koff);
      acc[nt] = __builtin_amdgcn_mfma_f32_16x16x32_bf16(a, bb, acc[nt], 0, 0, 0);
    }
  }

  float p[13][4];
  #pragma unroll
  for (int nt = 0; nt < 13; ++nt)
    #pragma unroll
    for (int r = 0; r < 4; ++r) {
      float v = acc[nt][r] * 0.125f;
      if (nt == 12 && l16 >= 4) v = -1e30f;
      p[nt][r] = v;
    }

  #pragma unroll
  for (int r = 0; r < 4; ++r) {
    float mx = -1e30f;
    #pragma unroll
    for (int nt = 0; nt < 13; ++nt) mx = fmaxf(mx, p[nt][r]);
    #pragma unroll
    for (int d = 1; d < 16; d <<= 1) mx = fmaxf(mx, __shfl_xor(mx, d, 64));
    float sm = 0.f;
    #pragma unroll
    for (int nt = 0; nt < 13; ++nt) {
      float e = __expf(p[nt][r] - mx);
      p[nt][r] = e;
      sm += e;
    }
    #pragma unroll
    for (int d = 1; d < 16; d <<= 1) sm += __shfl_xor(sm, d, 64);
    float inv = 1.0f / sm;
    #pragma unroll
    for (int nt = 0; nt < 13; ++nt) p[nt][r] *= inv;
  }

  #pragma unroll
  for (int nt = 0; nt < 13; ++nt)
    #pragma unroll
    for (int r = 0; r < 4; ++r)
      Pl[(quad * 4 + r) * 232 + nt * 16 + l16] = (bf16_t)p[nt][r];
  __syncthreads();

  f32x4 pv[4];
  #pragma unroll
  for (int nt = 0; nt < 4; ++nt) pv[nt] = zero;
  const bf16_t* Vb = Vt + (long)bh * 64 * 224;
  #pragma unroll
  for (int ks = 0; ks < 7; ++ks) {
    bf16x8 a = *(const bf16x8*)(Pl + l16 * 232 + ks * 32 + quad * 8);
    #pragma unroll
    for (int nt = 0; nt < 4; ++nt) {
      bf16x8 bb = *(const bf16x8*)(Vb + (long)(nt * 16 + l16) * 224 + ks * 32 + quad * 8);
      pv[nt] = __builtin_amdgcn_mfma_f32_16x16x32_bf16(a, bb, pv[nt], 0, 0, 0);
    }
  }

  #pragma unroll
  for (int nt = 0; nt < 4; ++nt)
    #pragma unroll
    for (int r = 0; r < 4; ++r) {
      int t = mt * 16 + quad * 4 + r;
      if (t < 196)
        att[(long)(b * 196 + t) * 768 + h * 64 + nt * 16 + l16] = (bf16_t)pv[nt][r];
    }
}

// ---------------------------------------------------------------------------
// Mean pool + final MLP2 partial reduction (4 partials) + bias
// ---------------------------------------------------------------------------
__global__ __launch_bounds__(256) void meanpool_fuse(
    const float* __restrict__ h, const bf16_t* __restrict__ pbuf,
    const float* __restrict__ bias, bf16_t* __restrict__ hm)
{
  int d = blockIdx.y * 256 + threadIdx.x;
  int b = blockIdx.x;
  float s = 0.f;
  for (int t = 0; t < 196; ++t) {
    long idx = (long)(b * 196 + t) * 768 + d;
    float v = h[idx];
    #pragma unroll
    for (int pp = 0; pp < 4; ++pp) v += (float)pbuf[idx + pp * PSTRIDE];
    s += v;
  }
  hm[b * 768 + d] = (bf16_t)(s * (1.0f / 196.0f) + bias[d]);
}

// ---------------------------------------------------------------------------
// Host launch
// ---------------------------------------------------------------------------
extern "C" void kernel_launch(void* const* d_in, const int* in_sizes, int n_in,
                              void* d_out, int out_size, void* d_ws, size_t ws_size,
                              hipStream_t stream)
{
  const float* x       = (const float*)d_in[0];
  const float* embed_W = (const float*)d_in[1];
  const float* embed_b = (const float*)d_in[2];
  const float* Wq      = (const float*)d_in[3];
  const float* Wk      = (const float*)d_in[4];
  const float* Wv      = (const float*)d_in[5];
  const float* Wo      = (const float*)d_in[6];
  const float* bo      = (const float*)d_in[7];
  const float* ln1_g   = (const float*)d_in[8];
  const float* ln1_b   = (const float*)d_in[9];
  const float* ln2_g   = (const float*)d_in[10];
  const float* ln2_b   = (const float*)d_in[11];
  const float* W1      = (const float*)d_in[12];
  const float* b1      = (const float*)d_in[13];
  const float* W2      = (const float*)d_in[14];
  const float* b2      = (const float*)d_in[15];
  const float* head_W  = (const float*)d_in[16];

  char* p = (char*)d_ws;
  auto carve = [&](size_t bytes) {
    char* r = p;
    p += (bytes + 255) & ~(size_t)255;
    return r;
  };
  bf16_t* embed_Wt = (bf16_t*)carve(589824ull * 2);
  bf16_t* qkvT     = (bf16_t*)carve(21233664ull * 2);
  bf16_t* WoT      = (bf16_t*)carve(7077888ull * 2);
  bf16_t* W1T      = (bf16_t*)carve(28311552ull * 2);
  bf16_t* W2T      = (bf16_t*)carve(28311552ull * 2);
  bf16_t* headWt   = (bf16_t*)carve(786432ull * 2);
  bf16_t* patches  = (bf16_t*)carve(4816896ull * 2);
  float*  h        = (float*)carve(4816896ull * 4);
  bf16_t* xn       = (bf16_t*)carve(4816896ull * 2);
  bf16_t* qkv      = (bf16_t*)carve(14487552ull * 2);
  bf16_t* Vt       = (bf16_t*)carve(5505024ull * 2);
  bf16_t* hmlp     = (bf16_t*)carve(19267584ull * 2);
  bf16_t* att      = (bf16_t*)carve(4816896ull * 2);
  bf16_t* pbuf     = (bf16_t*)carve(4ull * PSTRIDE * 2);
  bf16_t* hm       = (bf16_t*)carve(98304ull * 2);
  (void)ws_size; (void)n_in; (void)in_sizes; (void)out_size;

  dim3 tb32(32, 8);

  tcvt<<<dim3(24, 24, 1),   tb32, 0, stream>>>(embed_W, embed_Wt, 768, 768, 0, 0, 0, 1);
  tcvt<<<dim3(24, 24, 12),  tb32, 0, stream>>>(Wo, WoT, 768, 768, 589824, 589824, 0, 1);
  tcvt<<<dim3(2, 24, 144),  tb32, 0, stream>>>(Wq, qkvT,           768, 64, 49152, 1769472, 49152, 12);
  tcvt<<<dim3(2, 24, 144),  tb32, 0, stream>>>(Wk, qkvT + 589824,  768, 64, 49152, 1769472, 49152, 12);
  tcvt<<<dim3(2, 24, 144),  tb32, 0, stream>>>(Wv, qkvT + 1179648, 768, 64, 49152, 1769472, 49152, 12);
  tcvt<<<dim3(96, 24, 12),  tb32, 0, stream>>>(W1, W1T, 768, 3072, 2359296, 2359296, 0, 1);
  tcvt<<<dim3(24, 96, 12),  tb32, 0, stream>>>(W2, W2T, 3072, 768, 2359296, 2359296, 0, 1);
  tcvt<<<dim3(32, 24, 1),   tb32, 0, stream>>>(head_W, headWt, 768, 1000, 0, 0, 0, 1);

  patchify<<<18816, 256, 0, stream>>>(x, patches);
  hinit<<<588, 256, 0, stream>>>(embed_b, h);
  vpad<<<2688, 256, 0, stream>>>(Vt);

  gemm_bt<5, 768, 2><<<BMPAD * 6 * 2, 256, 0, stream>>>(
      patches, embed_Wt, 768, 6272, 768, nullptr, nullptr, pbuf, nullptr);

  for (int l = 0; l < NLAYER; ++l) {
    ln_fuse<<<1568, 256, 0, stream>>>(
        h, pbuf, l == 0 ? 2 : 4, l == 0 ? nullptr : b2 + (l - 1) * 768,
        ln1_g + l * 768, ln1_b + l * 768, xn);
    gemm_bt<6, 768, 1><<<BMPAD * 18, 256, 0, stream>>>(
        xn, qkvT + (long)l * 1769472, 2304, 6272, 2304,
        nullptr, nullptr, qkv, Vt);
    attn_fused<<<dim3(13, 384), 64, 0, stream>>>(qkv, Vt, att);
    gemm_bt<5, 768, 2><<<BMPAD * 6 * 2, 256, 0, stream>>>(
        att, WoT + (long)l * 589824, 768, 6272, 768,
        nullptr, nullptr, pbuf, nullptr);
    ln_fuse<<<1568, 256, 0, stream>>>(
        h, pbuf, 2, bo + l * 768, ln2_g + l * 768, ln2_b + l * 768, xn);
    gemm_bt<3, 768, 1><<<BMPAD * 24, 256, 0, stream>>>(
        xn, W1T + (long)l * 2359296, 3072, 6272, 3072,
        b1 + l * 3072, nullptr, hmlp, nullptr);
    gemm_bt<5, 3072, 4><<<BMPAD * 6 * 4, 256, 0, stream>>>(
        hmlp, W2T + (long)l * 2359296, 768, 6272, 768,
        nullptr, nullptr, pbuf, nullptr);
  }

  meanpool_fuse<<<dim3(32, 3), 256, 0, stream>>>(h, pbuf, b2 + 11 * 768, hm);
  gemm_bt<4, 768, 1><<<BMPAD * 8, 256, 0, stream>>>(
      hm, headWt, 1000, 32, 1000, nullptr, (float*)d_out, nullptr, nullptr);
}